// Round 20
// baseline (648.148 us; speedup 1.0000x reference)
//
#include <hip/hip_runtime.h>
#include <hip/hip_bf16.h>

// MoE E=64, top-2, T=8192, D=1024, DFF=1408. Round 20 (base = r19, single
// change: ffn2 K-step 32 -> 64, halving its barrier-step count 44 -> 22):
//  - r14-r19 established time ~ steps x fixed latency (~2900cy/step,
//    FLOP-independent). ffn2 has register headroom (acc=64) to double BK.
//  - ffn2: 8x dwordx4 B loads/thread (8 krows x 4 cols), 4 short8 LDS
//    writes, A-frags 2 k-halves, 32 MFMA/step, LDS 2x16KB, (256,2).
//  - ffn1 and all other kernels identical to r19.

#define S_ 2048
#define B_ 4
#define D_ 1024
#define DFF_ 1408
#define E_ 64
#define T_ 8192
#define KTOP_ 2
#define NPAIR_ (T_*KTOP_)
#define PAD_ 384
#define ROWS_ (E_*PAD_)

#define BM 128
#define BN 128
#define BK 32
#define BK2 64

typedef __attribute__((ext_vector_type(8))) short short8;
typedef __attribute__((ext_vector_type(4))) short s16x4;
typedef __attribute__((ext_vector_type(4))) float f32x4;
typedef __attribute__((ext_vector_type(4))) unsigned short us4;

// ---------------- workspace layout (bytes) ----------------
constexpr size_t OFF_PROBS  = 0;
constexpr size_t OFF_PE     = OFF_PROBS + (size_t)T_*E_*4;
constexpr size_t OFF_PW     = OFF_PE + (size_t)NPAIR_*4;
constexpr size_t OFF_COUNTS = OFF_PW + (size_t)NPAIR_*4;
constexpr size_t OFF_CURSOR = OFF_COUNTS + 256;
constexpr size_t OFF_MESUM  = OFF_CURSOR + 256;
constexpr size_t OFF_ROWTOK = OFF_MESUM + 256;
constexpr size_t OFF_ROWW   = OFF_ROWTOK + (size_t)ROWS_*4;
constexpr size_t OFF_XBUF   = OFF_ROWW + (size_t)ROWS_*4;     // octet-major bf16
constexpr size_t OFF_H      = OFF_XBUF + (size_t)ROWS_*D_*2;  // octet-major bf16

__device__ __forceinline__ short f2bfs(float f) {
  union { __hip_bfloat16 h; short s; } u;
  u.h = __float2bfloat16(f);
  return u.s;
}

// granule XOR swizzle for B staging (conflict-free frag reads)
__device__ __forceinline__ int SWZ(int g) { return g ^ (((g >> 4) & 3) << 1); }

#define BARS() do {                                  \
    __builtin_amdgcn_sched_barrier(0);               \
    __builtin_amdgcn_s_barrier();                    \
    __builtin_amdgcn_sched_barrier(0);               \
  } while (0)
#define BARX() __builtin_amdgcn_s_barrier()
#define WAIT_LGKM0() asm volatile("s_waitcnt lgkmcnt(0)" ::: "memory")

// ---------------- gate v2 ----------------
__device__ __forceinline__ float softmax64(float acc, int lane) {
  float m = acc;
  for (int o = 32; o; o >>= 1) m = fmaxf(m, __shfl_xor(m, o));
  float p = expf(acc - m);
  float s = p;
  for (int o = 32; o; o >>= 1) s += __shfl_xor(s, o);
  return p / s;
}

__device__ __forceinline__ void topk_write(float p, int t, int lane,
    float* __restrict__ probs, int* __restrict__ pe, float* __restrict__ pw,
    int* __restrict__ counts) {
  probs[(size_t)t * E_ + lane] = p;
  float v1 = p; int i1 = lane;
  for (int o = 32; o; o >>= 1) {
    float ov = __shfl_xor(v1, o); int oi = __shfl_xor(i1, o);
    if (ov > v1 || (ov == v1 && oi < i1)) { v1 = ov; i1 = oi; }
  }
  float v2 = (lane == i1) ? -1.f : p; int i2 = lane;
  for (int o = 32; o; o >>= 1) {
    float ov = __shfl_xor(v2, o); int oi = __shfl_xor(i2, o);
    if (ov > v2 || (ov == v2 && oi < i2)) { v2 = ov; i2 = oi; }
  }
  if (lane == 0) {
    float wsum = v1 + v2;
    pe[2 * t]     = i1; pw[2 * t]     = v1 / wsum;
    pe[2 * t + 1] = i2; pw[2 * t + 1] = v2 / wsum;
    atomicAdd(&counts[i1], 1);
    atomicAdd(&counts[i2], 1);
  }
}

__global__ __launch_bounds__(256) void gate_kernel(
    const float* __restrict__ x, const float* __restrict__ Wg,
    float* __restrict__ probs, int* __restrict__ pe, float* __restrict__ pw,
    int* __restrict__ counts) {
  int t0 = blockIdx.x * 8;
  int tid = threadIdx.x;
  int lane = tid & 63, wv = tid >> 6;
  __shared__ float tk[8][D_];
  for (int u = tid; u < 8 * (D_ / 4); u += 256) {
    int r = u >> 8, c4 = u & 255;
    int t = t0 + r;
    int b = t >> 11, s = t & (S_ - 1);
    ((float4*)tk[r])[c4] = ((const float4*)(x + (size_t)(s * B_ + b) * D_))[c4];
  }
  __syncthreads();
  const float* tkA = tk[2 * wv];
  const float* tkB = tk[2 * wv + 1];
  float acc0 = 0.f, acc1 = 0.f;
  #pragma unroll 8
  for (int d = 0; d < D_; ++d) {
    float w = Wg[(size_t)d * E_ + lane];
    acc0 += tkA[d] * w;
    acc1 += tkB[d] * w;
  }
  int ta = t0 + 2 * wv, tb = ta + 1;
  float p0 = softmax64(acc0, lane);
  float p1 = softmax64(acc1, lane);
  topk_write(p0, ta, lane, probs, pe, pw, counts);
  topk_write(p1, tb, lane, probs, pe, pw, counts);
}

// ---------------- me reduce ----------------
__global__ __launch_bounds__(256) void me_kernel(const float* __restrict__ probs,
                                                 float* __restrict__ mesum) {
  int e = blockIdx.x, tid = threadIdx.x;
  float a = 0.f;
  for (int t = tid; t < T_; t += 256) a += probs[(size_t)t * E_ + e];
  __shared__ float red[256];
  red[tid] = a; __syncthreads();
  for (int s = 128; s; s >>= 1) {
    if (tid < s) red[tid] += red[tid + s];
    __syncthreads();
  }
  if (tid == 0) mesum[e] = red[0];
}

// ---------------- finalize l_aux ----------------
__global__ __launch_bounds__(64) void finalize_kernel(
    const int* __restrict__ counts, const float* __restrict__ mesum,
    float* __restrict__ laux_out) {
  int lane = threadIdx.x;
  float contrib = (mesum[lane] / (float)T_) * ((float)counts[lane] / (float)(T_ * KTOP_));
  for (int o = 32; o; o >>= 1) contrib += __shfl_xor(contrib, o);
  if (lane == 0) laux_out[0] = (float)E_ * contrib;
}

// ---------------- scatter: token rows -> OCTET-MAJOR bf16 xbuf ----------------
// xbufO[e][o][m][8]: elem offset = e*D*PAD + (o*PAD + m)*8, o = k/8 in [0,128)
__global__ __launch_bounds__(64) void scatter_kernel(
    const float* __restrict__ x, const int* __restrict__ pe, const float* __restrict__ pw,
    int* __restrict__ cursor, int* __restrict__ rowtok, float* __restrict__ roww,
    unsigned short* __restrict__ xbufO) {
  int p = blockIdx.x;
  int lane = threadIdx.x;
  __shared__ int srow;
  __shared__ int sexp;
  if (lane == 0) {
    int e = pe[p];
    int slot = atomicAdd(&cursor[e], 1);
    int row = (slot < PAD_) ? slot : -1;
    if (row >= 0) { rowtok[e * PAD_ + row] = p >> 1; roww[e * PAD_ + row] = pw[p]; }
    srow = row; sexp = e;
  }
  __syncthreads();
  int m = srow;
  if (m < 0) return;
  int e = sexp;
  int t = p >> 1;
  int b = t >> 11, s = t & (S_ - 1);
  const float4* src = (const float4*)(x + (size_t)(s * B_ + b) * D_);
  unsigned short* dstE = xbufO + (size_t)e * D_ * PAD_;
  #pragma unroll
  for (int oo = 0; oo < 2; ++oo) {
    int o = lane + oo * 64;
    float4 lo = src[o * 2], hi = src[o * 2 + 1];
    short8 g;
    g[0] = f2bfs(lo.x); g[1] = f2bfs(lo.y); g[2] = f2bfs(lo.z); g[3] = f2bfs(lo.w);
    g[4] = f2bfs(hi.x); g[5] = f2bfs(hi.y); g[6] = f2bfs(hi.z); g[7] = f2bfs(hi.w);
    *(short8*)(dstE + ((size_t)o * PAD_ + m) * 8) = g;
  }
}

// ---------------- ffn1: 128x128 tile, interleaved load-issue (r19) ----------------
__global__ __launch_bounds__(256, 2) void ffn1_kernel(
    const unsigned short* __restrict__ xbufO, const float* __restrict__ W1,
    const float* __restrict__ W3, const int* __restrict__ counts,
    unsigned short* __restrict__ hO) {
  // grid 2112 = 8 xcd x (8 eg x 11 ni x 3 mb), mb fastest (W L2 sharing)
  int bid = blockIdx.x;
  int r = bid & 7, u = bid >> 3;
  int mb = u % 3; int v = u / 3;
  int ni = v % 11; int eg = v / 11;
  int e = eg * 8 + r;
  int n0 = ni * BN;
  int m0 = mb * BM;
  int Me = min(counts[e], PAD_);
  if (m0 >= Me) return;                  // block-granular pad skip

  const unsigned short* AO = xbufO + (size_t)e * D_ * PAD_;
  const float* B1p = W1 + (size_t)e * D_ * DFF_ + n0;
  const float* B3p = W3 + (size_t)e * D_ * DFF_ + n0;
  unsigned short* hE = hO + (size_t)e * PAD_ * DFF_;

  __shared__ short B1s[2 * BK * BN];   // 2 x 8KB
  __shared__ short B3s[2 * BK * BN];   // 2 x 8KB
  __shared__ short Hb[BM * BN];        // 32KB epilogue transpose bounce

  int tid = threadIdx.x;
  int lane = tid & 63;
  int wv = tid >> 6, wr = wv >> 1, wc = wv & 1;

  // B staging: tid<128 -> W1, >=128 -> W3. Thread: 8 k-rows x 4 cols.
  int msel = tid >> 7;
  int t7 = tid & 127;
  int col4 = t7 & 31;
  int krow0 = (t7 >> 5) << 3;
  const float* qB = (msel ? B3p : B1p) + (size_t)krow0 * DFF_ + col4 * 4;
  char* Bdst = (char*)(msel ? B3s : B1s);
  int kseg = krow0 >> 3;
  int boffc[4];
  #pragma unroll
  for (int cc = 0; cc < 4; ++cc) {
    int c = col4 * 4 + cc;
    boffc[cc] = ((c >> 4) << 10) + (SWZ((kseg << 4) + (c & 15)) << 4);
  }

  // A-direct: frag f=wr*4+mi; lane: row m0+f*16+(lane&15), octet 4t+(lane>>4)
  const unsigned short* qa =
      AO + (((size_t)(lane >> 4)) * PAD_ + m0 + (wr << 6) + (lane & 15)) * 8;

  short8 afE[4], afO[4];
  f32x4 fBE[8], fBO[8];
  f32x4 acc1[4][4] = {};
  f32x4 acc3[4][4] = {};

#define F1_ALOAD(SET) do {                                               \
    _Pragma("unroll")                                                    \
    for (int mi = 0; mi < 4; ++mi)                                       \
      af##SET[mi] = *(const short8*)(qa + mi * 128);                     \
    qa += (size_t)4 * PAD_ * 8;                                          \
  } while (0)

#define F1_BLOAD(SET) do {                                               \
    _Pragma("unroll")                                                    \
    for (int j = 0; j < 8; ++j)                                          \
      fB##SET[j] = *(const f32x4*)(qB + (size_t)j * DFF_);               \
    qB += (size_t)BK * DFF_;                                             \
  } while (0)

#define F1_BWRITE(SET, BUF) do {                                         \
    _Pragma("unroll")                                                    \
    for (int cc = 0; cc < 4; ++cc) {                                     \
      short8 w;                                                          \
      _Pragma("unroll")                                                  \
      for (int j = 0; j < 8; ++j) w[j] = f2bfs(fB##SET[j][cc]);          \
      *(short8*)(Bdst + (BUF)*8192 + boffc[cc]) = w;                     \
    }                                                                    \
  } while (0)

#define F1_MFMA(BUF, SET) do {                                           \
    int lsw = SWZ(lane) << 4;                                            \
    __builtin_amdgcn_s_setprio(1);                                       \
    _Pragma("unroll")                                                    \
    for (int q = 0; q < 4; ++q) {                                        \
      short8 bf1 = *(const short8*)((char*)B1s + (BUF)*8192 + (((wc << 2) + q) << 10) + lsw); \
      short8 bf3 = *(const short8*)((char*)B3s + (BUF)*8192 + (((wc << 2) + q) << 10) + lsw); \
      _Pragma("unroll")                                                  \
      for (int mi = 0; mi < 4; ++mi) {                                   \
        acc1[mi][q] = __builtin_amdgcn_mfma_f32_16x16x32_bf16(af##SET[mi], bf1, acc1[mi][q], 0, 0, 0); \
        acc3[mi][q] = __builtin_amdgcn_mfma_f32_16x16x32_bf16(af##SET[mi], bf3, acc3[mi][q], 0, 0, 0); \
      }                                                                  \
    }                                                                    \
    __builtin_amdgcn_s_setprio(0);                                       \
  } while (0)

  // 32 K-tiles, depth-2, interleaved issue (r19)
  F1_ALOAD(E); F1_BLOAD(E);      // t0
  F1_ALOAD(O); F1_BLOAD(O);      // t1
  for (int it = 0; it < 15; ++it) {
    F1_BWRITE(E, 0); WAIT_LGKM0(); BARS();
    F1_BLOAD(E);
    F1_MFMA(0, E);
    F1_ALOAD(E);
    BARX();
    F1_BWRITE(O, 1); WAIT_LGKM0(); BARS();
    F1_BLOAD(O);
    F1_MFMA(1, O);
    F1_ALOAD(O);
    BARX();
  }
  F1_BWRITE(E, 0); WAIT_LGKM0(); BARS(); F1_MFMA(0, E); BARX();
  F1_BWRITE(O, 1); WAIT_LGKM0(); BARS(); F1_MFMA(1, O);

  // epilogue: silu(acc1)*acc3 -> Hb (C-layout) -> octet-major hO
  __syncthreads();
  int lr = (lane >> 4) << 2, lc = lane & 15;
  #pragma unroll
  for (int mi = 0; mi < 4; ++mi) {
    #pragma unroll
    for (int j = 0; j < 4; ++j) {
      int m = ((wr << 2) + mi) * 16 + lr + j;       // local row 0..127
      #pragma unroll
      for (int q = 0; q < 4; ++q) {
        int c = (wc << 6) + (q << 4) + lc;          // local col 0..127
        float a = acc1[mi][q][j];
        float gt = a / (1.f + __expf(-a));
        Hb[((size_t)(c >> 3) * BM + m) * 8 + (c & 7)] = f2bfs(gt * acc3[mi][q][j]);
      }
    }
  }
  __syncthreads();
  int co = tid >> 4, ml0 = (tid & 15) << 3;         // 16 col-octets x 16 row-groups
  size_t fo = (size_t)(n0 >> 3) + co;
  #pragma unroll
  for (int i = 0; i < 8; ++i) {
    int ml = ml0 + i;
    short8 vq = *(const short8*)(Hb + ((size_t)co * BM + ml) * 8);
    *(short8*)(hE + (fo * PAD_ + m0 + ml) * 8) = vq;
  }
}

// ---------------- ffn2: 128x128 tile, BK=64 (22 steps) ----------------
__global__ __launch_bounds__(256, 2) void ffn2_kernel(
    const unsigned short* __restrict__ hO, const float* __restrict__ W2,
    const int* __restrict__ counts, const int* __restrict__ rowtok,
    const float* __restrict__ roww, float* __restrict__ y) {
  // grid 1536 = 8 xcd x (8 eg x 8 ni x 3 mb), mb fastest
  int bid = blockIdx.x;
  int r = bid & 7, u = bid >> 3;
  int mb = u % 3; int v = u / 3;
  int ni = v % 8; int eg = v / 8;
  int e = eg * 8 + r;
  int n0 = ni * BN;
  int m0 = mb * BM;
  int Me = min(counts[e], PAD_);
  if (m0 >= Me) return;

  const unsigned short* AO = hO + (size_t)e * PAD_ * DFF_;
  const float* Bw = W2 + (size_t)e * DFF_ * D_ + n0;

  __shared__ short Bs[2 * BK2 * BN];   // 2 x 16KB: [buf][half(8KB)][cb(1KB)][granule]

  int tid = threadIdx.x;
  int lane = tid & 63;
  int wv = tid >> 6, wr = wv >> 1, wc = wv & 1;

  // B staging: thread owns 8 k-rows x 4 cols (8x dwordx4 loads; 4x short8
  // granule writes, all rows in one granule since krow0 is 8-aligned).
  int col4 = tid & 31;
  int krow0 = (tid >> 5) << 3;           // 0,8,...,56
  const float* qB = Bw + (size_t)krow0 * D_ + col4 * 4;
  int half = krow0 >> 5;                 // k-half 0..1
  int kseg = (krow0 >> 3) & 3;
  int boffc[4];
  #pragma unroll
  for (int cc = 0; cc < 4; ++cc) {
    int c = col4 * 4 + cc;
    boffc[cc] = half * 8192 + ((c >> 4) << 10) + (SWZ((kseg << 4) + (c & 15)) << 4);
  }

  // A-direct: frag (mi, h): row m0+(wr*4+mi)*16+(lane&15),
  // octet 8t + h*4 + (lane>>4)
  const unsigned short* qa =
      AO + (((size_t)(lane >> 4)) * PAD_ + m0 + (wr << 6) + (lane & 15)) * 8;

  short8 afE[8], afO[8];                 // index (h<<2)+mi
  f32x4 fBE[8], fBO[8];
  f32x4 acc[4][4] = {};

#define F2_ALOAD(SET) do {                                               \
    _Pragma("unroll")                                                    \
    for (int h = 0; h < 2; ++h)                                          \
      _Pragma("unroll")                                                  \
      for (int mi = 0; mi < 4; ++mi)                                     \
        af##SET[(h << 2) + mi] =                                         \
            *(const short8*)(qa + (size_t)h * 4 * PAD_ * 8 + mi * 128);  \
    qa += (size_t)8 * PAD_ * 8;                                          \
  } while (0)

#define F2_BLOAD(SET) do {                                               \
    _Pragma("unroll")                                                    \
    for (int j = 0; j < 8; ++j)                                          \
      fB##SET[j] = *(const f32x4*)(qB + (size_t)j * D_);                 \
    qB += (size_t)BK2 * D_;                                              \
  } while (0)

#define F2_BWRITE(SET, BUF) do {                                         \
    _Pragma("unroll")                                                    \
    for (int cc = 0; cc < 4; ++cc) {                                     \
      short8 w;                                                          \
      _Pragma("unroll")                                                  \
      for (int j = 0; j < 8; ++j) w[j] = f2bfs(fB##SET[j][cc]);          \
      *(short8*)((char*)Bs + (BUF)*16384 + boffc[cc]) = w;               \
    }                                                                    \
  } while (0)

#define F2_MFMA(BUF, SET) do {                                           \
    int lsw = SWZ(lane) << 4;                                            \
    __builtin_amdgcn_s_setprio(1);                                       \
    _Pragma("unroll")                                                    \
    for (int h = 0; h < 2; ++h)                                          \
      _Pragma("unroll")                                                  \
      for (int q = 0; q < 4; ++q) {                                      \
        short8 bfr = *(const short8*)((char*)Bs + (BUF)*16384 + h * 8192 \
                                      + (((wc << 2) + q) << 10) + lsw);  \
        _Pragma("unroll")                                                \
        for (int mi = 0; mi < 4; ++mi)                                   \
          acc[mi][q] = __builtin_amdgcn_mfma_f32_16x16x32_bf16(          \
              af##SET[(h << 2) + mi], bfr, acc[mi][q], 0, 0, 0);         \
      }                                                                  \
    __builtin_amdgcn_s_setprio(0);                                       \
  } while (0)

  // 22 K-tiles of 64, depth-2, interleaved issue
  F2_ALOAD(E); F2_BLOAD(E);      // t0
  F2_ALOAD(O); F2_BLOAD(O);      // t1
  for (int it = 0; it < 10; ++it) {
    F2_BWRITE(E, 0); WAIT_LGKM0(); BARS();
    F2_BLOAD(E);                 // t(2it+2)
    F2_MFMA(0, E);
    F2_ALOAD(E);
    BARX();
    F2_BWRITE(O, 1); WAIT_LGKM0(); BARS();
    F2_BLOAD(O);                 // t(2it+3)
    F2_MFMA(1, O);
    F2_ALOAD(O);
    BARX();
  }
  F2_BWRITE(E, 0); WAIT_LGKM0(); BARS(); F2_MFMA(0, E); BARX();
  F2_BWRITE(O, 1); WAIT_LGKM0(); BARS(); F2_MFMA(1, O);

  int lr = (lane >> 4) << 2, lc = lane & 15;
  #pragma unroll
  for (int mi = 0; mi < 4; ++mi) {
    #pragma unroll
    for (int j = 0; j < 4; ++j) {
      int m = m0 + ((wr << 2) + mi) * 16 + lr + j;
      if (m < Me) {
        int rw = e * PAD_ + m;
        int t = rowtok[rw];
        float w = roww[rw];
        int b = t >> 11, s = t & (S_ - 1);
        float* yp = y + (size_t)(s * B_ + b) * D_ + n0 + (wc << 6) + lc;
        #pragma unroll
        for (int q = 0; q < 4; ++q)
          atomicAdd(&yp[q << 4], w * acc[mi][q][j]);   // exactly 2 adds/elem
      }
    }
  }
}

extern "C" void kernel_launch(void* const* d_in, const int* in_sizes, int n_in,
                              void* d_out, int out_size, void* d_ws, size_t ws_size,
                              hipStream_t stream) {
  const float* x  = (const float*)d_in[0];
  const float* Wg = (const float*)d_in[1];
  const float* W1 = (const float*)d_in[2];
  const float* W3 = (const float*)d_in[3];
  const float* W2 = (const float*)d_in[4];
  float* y = (float*)d_out;
  float* laux = y + (size_t)S_ * B_ * D_;

  char* ws = (char*)d_ws;
  float* probs  = (float*)(ws + OFF_PROBS);
  int*   pe     = (int*)  (ws + OFF_PE);
  float* pw     = (float*)(ws + OFF_PW);
  int*   counts = (int*)  (ws + OFF_COUNTS);
  int*   cursor = (int*)  (ws + OFF_CURSOR);
  float* mesum  = (float*)(ws + OFF_MESUM);
  int*   rowtok = (int*)  (ws + OFF_ROWTOK);
  float* roww   = (float*)(ws + OFF_ROWW);
  unsigned short* xbufO = (unsigned short*)(ws + OFF_XBUF);
  unsigned short* hO    = (unsigned short*)(ws + OFF_H);

  hipMemsetAsync(d_out, 0, (size_t)out_size * sizeof(float), stream);
  hipMemsetAsync(counts, 0, 512, stream);  // counts + cursor

  gate_kernel<<<T_ / 8, 256, 0, stream>>>(x, Wg, probs, pe, pw, counts);
  me_kernel<<<E_, 256, 0, stream>>>(probs, mesum);
  finalize_kernel<<<1, 64, 0, stream>>>(counts, mesum, laux);
  scatter_kernel<<<NPAIR_, 64, 0, stream>>>(x, pe, pw, cursor, rowtok, roww, xbufO);
  ffn1_kernel<<<8 * 8 * 11 * 3, 256, 0, stream>>>(xbufO, W1, W3, counts, hO);
  ffn2_kernel<<<8 * 8 * 8 * 3, 256, 0, stream>>>(hO, W2, counts, rowtok, roww, y);
}

// Round 21
// 579.874 us; speedup vs baseline: 1.1177x; 1.1177x over previous
//
#include <hip/hip_runtime.h>
#include <hip/hip_bf16.h>

// MoE E=64, top-2, T=8192, D=1024, DFF=1408. Round 21 (base = r19, single
// change: scatter FUSED into gate):
//  - gate already holds the 8 tokens in LDS; after top-2 it writes the 16
//    routed rows directly to octet-major xbufO (half-block per row, granule
//    per thread). Eliminates the 16384-block scatter launch, the 64MB x
//    re-read, and the pe/pw round trip. counts==cursor unified (one atomic).
//  - ffn1/ffn2 = r19 verbatim (r20's ffn2 BK=64 was neutral; reverted).

#define S_ 2048
#define B_ 4
#define D_ 1024
#define DFF_ 1408
#define E_ 64
#define T_ 8192
#define KTOP_ 2
#define NPAIR_ (T_*KTOP_)
#define PAD_ 384
#define ROWS_ (E_*PAD_)

#define BM 128
#define BN 128
#define BK 32

typedef __attribute__((ext_vector_type(8))) short short8;
typedef __attribute__((ext_vector_type(4))) short s16x4;
typedef __attribute__((ext_vector_type(4))) float f32x4;
typedef __attribute__((ext_vector_type(4))) unsigned short us4;

// ---------------- workspace layout (bytes) ----------------
constexpr size_t OFF_PROBS  = 0;
constexpr size_t OFF_COUNTS = OFF_PROBS + (size_t)T_*E_*4;
constexpr size_t OFF_MESUM  = OFF_COUNTS + 512;
constexpr size_t OFF_ROWTOK = OFF_MESUM + 256;
constexpr size_t OFF_ROWW   = OFF_ROWTOK + (size_t)ROWS_*4;
constexpr size_t OFF_XBUF   = OFF_ROWW + (size_t)ROWS_*4;     // octet-major bf16
constexpr size_t OFF_H      = OFF_XBUF + (size_t)ROWS_*D_*2;  // octet-major bf16

__device__ __forceinline__ short f2bfs(float f) {
  union { __hip_bfloat16 h; short s; } u;
  u.h = __float2bfloat16(f);
  return u.s;
}

// granule XOR swizzle for B staging (conflict-free frag reads)
__device__ __forceinline__ int SWZ(int g) { return g ^ (((g >> 4) & 3) << 1); }

#define BARS() do {                                  \
    __builtin_amdgcn_sched_barrier(0);               \
    __builtin_amdgcn_s_barrier();                    \
    __builtin_amdgcn_sched_barrier(0);               \
  } while (0)
#define BARX() __builtin_amdgcn_s_barrier()
#define WAIT_LGKM0() asm volatile("s_waitcnt lgkmcnt(0)" ::: "memory")

// ---------------- gate + fused scatter ----------------
__device__ __forceinline__ float softmax64(float acc, int lane) {
  float m = acc;
  for (int o = 32; o; o >>= 1) m = fmaxf(m, __shfl_xor(m, o));
  float p = expf(acc - m);
  float s = p;
  for (int o = 32; o; o >>= 1) s += __shfl_xor(s, o);
  return p / s;
}

__global__ __launch_bounds__(256) void gate_kernel(
    const float* __restrict__ x, const float* __restrict__ Wg,
    float* __restrict__ probs, int* __restrict__ counts,
    int* __restrict__ rowtok, float* __restrict__ roww,
    unsigned short* __restrict__ xbufO) {
  int t0 = blockIdx.x * 8;
  int tid = threadIdx.x;
  int lane = tid & 63, wv = tid >> 6;
  __shared__ float tk[8][D_];
  __shared__ int sE[8][2];
  __shared__ int sM[8][2];
  for (int u = tid; u < 8 * (D_ / 4); u += 256) {
    int r = u >> 8, c4 = u & 255;
    int t = t0 + r;
    int b = t >> 11, s = t & (S_ - 1);
    ((float4*)tk[r])[c4] = ((const float4*)(x + (size_t)(s * B_ + b) * D_))[c4];
  }
  __syncthreads();
  const float* tkA = tk[2 * wv];
  const float* tkB = tk[2 * wv + 1];
  float acc0 = 0.f, acc1 = 0.f;
  #pragma unroll 8
  for (int d = 0; d < D_; ++d) {
    float w = Wg[(size_t)d * E_ + lane];
    acc0 += tkA[d] * w;
    acc1 += tkB[d] * w;
  }
  #pragma unroll
  for (int half = 0; half < 2; ++half) {
    float p = softmax64(half ? acc1 : acc0, lane);
    int tkn = 2 * wv + half;
    int t = t0 + tkn;
    probs[(size_t)t * E_ + lane] = p;
    float v1 = p; int i1 = lane;
    for (int o = 32; o; o >>= 1) {
      float ov = __shfl_xor(v1, o); int oi = __shfl_xor(i1, o);
      if (ov > v1 || (ov == v1 && oi < i1)) { v1 = ov; i1 = oi; }
    }
    float v2 = (lane == i1) ? -1.f : p; int i2 = lane;
    for (int o = 32; o; o >>= 1) {
      float ov = __shfl_xor(v2, o); int oi = __shfl_xor(i2, o);
      if (ov > v2 || (ov == v2 && oi < i2)) { v2 = ov; i2 = oi; }
    }
    if (lane == 0) {
      float wsum = v1 + v2;
      int s1 = atomicAdd(&counts[i1], 1);
      int s2 = atomicAdd(&counts[i2], 1);
      int m1 = (s1 < PAD_) ? s1 : -1;
      int m2 = (s2 < PAD_) ? s2 : -1;
      if (m1 >= 0) { rowtok[i1 * PAD_ + m1] = t; roww[i1 * PAD_ + m1] = v1 / wsum; }
      if (m2 >= 0) { rowtok[i2 * PAD_ + m2] = t; roww[i2 * PAD_ + m2] = v2 / wsum; }
      sE[tkn][0] = i1; sM[tkn][0] = m1;
      sE[tkn][1] = i2; sM[tkn][1] = m2;
    }
  }
  __syncthreads();
  // fused scatter: 16 (token,expert) rows; half-block per row, granule/thread
  int hh = tid >> 7, t7 = tid & 127;
  #pragma unroll
  for (int pp = 0; pp < 8; ++pp) {
    int pr = 2 * pp + hh;
    int tkn = pr >> 1, j = pr & 1;
    int e = sE[tkn][j];
    int m = sM[tkn][j];
    if (m >= 0) {
      const float* src = tk[tkn] + t7 * 8;
      short8 g;
      #pragma unroll
      for (int k = 0; k < 8; ++k) g[k] = f2bfs(src[k]);
      *(short8*)(xbufO + (size_t)e * D_ * PAD_ + ((size_t)t7 * PAD_ + m) * 8) = g;
    }
  }
}

// ---------------- me reduce ----------------
__global__ __launch_bounds__(256) void me_kernel(const float* __restrict__ probs,
                                                 float* __restrict__ mesum) {
  int e = blockIdx.x, tid = threadIdx.x;
  float a = 0.f;
  for (int t = tid; t < T_; t += 256) a += probs[(size_t)t * E_ + e];
  __shared__ float red[256];
  red[tid] = a; __syncthreads();
  for (int s = 128; s; s >>= 1) {
    if (tid < s) red[tid] += red[tid + s];
    __syncthreads();
  }
  if (tid == 0) mesum[e] = red[0];
}

// ---------------- finalize l_aux ----------------
__global__ __launch_bounds__(64) void finalize_kernel(
    const int* __restrict__ counts, const float* __restrict__ mesum,
    float* __restrict__ laux_out) {
  int lane = threadIdx.x;
  float contrib = (mesum[lane] / (float)T_) * ((float)counts[lane] / (float)(T_ * KTOP_));
  for (int o = 32; o; o >>= 1) contrib += __shfl_xor(contrib, o);
  if (lane == 0) laux_out[0] = (float)E_ * contrib;
}

// ---------------- ffn1: 128x128 tile, interleaved load-issue (r19) ----------------
__global__ __launch_bounds__(256, 2) void ffn1_kernel(
    const unsigned short* __restrict__ xbufO, const float* __restrict__ W1,
    const float* __restrict__ W3, const int* __restrict__ counts,
    unsigned short* __restrict__ hO) {
  // grid 2112 = 8 xcd x (8 eg x 11 ni x 3 mb), mb fastest (W L2 sharing)
  int bid = blockIdx.x;
  int r = bid & 7, u = bid >> 3;
  int mb = u % 3; int v = u / 3;
  int ni = v % 11; int eg = v / 11;
  int e = eg * 8 + r;
  int n0 = ni * BN;
  int m0 = mb * BM;
  int Me = min(counts[e], PAD_);
  if (m0 >= Me) return;                  // block-granular pad skip

  const unsigned short* AO = xbufO + (size_t)e * D_ * PAD_;
  const float* B1p = W1 + (size_t)e * D_ * DFF_ + n0;
  const float* B3p = W3 + (size_t)e * D_ * DFF_ + n0;
  unsigned short* hE = hO + (size_t)e * PAD_ * DFF_;

  __shared__ short B1s[2 * BK * BN];   // 2 x 8KB
  __shared__ short B3s[2 * BK * BN];   // 2 x 8KB
  __shared__ short Hb[BM * BN];        // 32KB epilogue transpose bounce

  int tid = threadIdx.x;
  int lane = tid & 63;
  int wv = tid >> 6, wr = wv >> 1, wc = wv & 1;

  // B staging: tid<128 -> W1, >=128 -> W3. Thread: 8 k-rows x 4 cols.
  int msel = tid >> 7;
  int t7 = tid & 127;
  int col4 = t7 & 31;
  int krow0 = (t7 >> 5) << 3;
  const float* qB = (msel ? B3p : B1p) + (size_t)krow0 * DFF_ + col4 * 4;
  char* Bdst = (char*)(msel ? B3s : B1s);
  int kseg = krow0 >> 3;
  int boffc[4];
  #pragma unroll
  for (int cc = 0; cc < 4; ++cc) {
    int c = col4 * 4 + cc;
    boffc[cc] = ((c >> 4) << 10) + (SWZ((kseg << 4) + (c & 15)) << 4);
  }

  // A-direct: frag f=wr*4+mi; lane: row m0+f*16+(lane&15), octet 4t+(lane>>4)
  const unsigned short* qa =
      AO + (((size_t)(lane >> 4)) * PAD_ + m0 + (wr << 6) + (lane & 15)) * 8;

  short8 afE[4], afO[4];
  f32x4 fBE[8], fBO[8];
  f32x4 acc1[4][4] = {};
  f32x4 acc3[4][4] = {};

#define F1_ALOAD(SET) do {                                               \
    _Pragma("unroll")                                                    \
    for (int mi = 0; mi < 4; ++mi)                                       \
      af##SET[mi] = *(const short8*)(qa + mi * 128);                     \
    qa += (size_t)4 * PAD_ * 8;                                          \
  } while (0)

#define F1_BLOAD(SET) do {                                               \
    _Pragma("unroll")                                                    \
    for (int j = 0; j < 8; ++j)                                          \
      fB##SET[j] = *(const f32x4*)(qB + (size_t)j * DFF_);               \
    qB += (size_t)BK * DFF_;                                             \
  } while (0)

#define F1_BWRITE(SET, BUF) do {                                         \
    _Pragma("unroll")                                                    \
    for (int cc = 0; cc < 4; ++cc) {                                     \
      short8 w;                                                          \
      _Pragma("unroll")                                                  \
      for (int j = 0; j < 8; ++j) w[j] = f2bfs(fB##SET[j][cc]);          \
      *(short8*)(Bdst + (BUF)*8192 + boffc[cc]) = w;                     \
    }                                                                    \
  } while (0)

#define F1_MFMA(BUF, SET) do {                                           \
    int lsw = SWZ(lane) << 4;                                            \
    __builtin_amdgcn_s_setprio(1);                                       \
    _Pragma("unroll")                                                    \
    for (int q = 0; q < 4; ++q) {                                        \
      short8 bf1 = *(const short8*)((char*)B1s + (BUF)*8192 + (((wc << 2) + q) << 10) + lsw); \
      short8 bf3 = *(const short8*)((char*)B3s + (BUF)*8192 + (((wc << 2) + q) << 10) + lsw); \
      _Pragma("unroll")                                                  \
      for (int mi = 0; mi < 4; ++mi) {                                   \
        acc1[mi][q] = __builtin_amdgcn_mfma_f32_16x16x32_bf16(af##SET[mi], bf1, acc1[mi][q], 0, 0, 0); \
        acc3[mi][q] = __builtin_amdgcn_mfma_f32_16x16x32_bf16(af##SET[mi], bf3, acc3[mi][q], 0, 0, 0); \
      }                                                                  \
    }                                                                    \
    __builtin_amdgcn_s_setprio(0);                                       \
  } while (0)

  // 32 K-tiles, depth-2, interleaved issue (r19)
  F1_ALOAD(E); F1_BLOAD(E);      // t0
  F1_ALOAD(O); F1_BLOAD(O);      // t1
  for (int it = 0; it < 15; ++it) {
    F1_BWRITE(E, 0); WAIT_LGKM0(); BARS();
    F1_BLOAD(E);
    F1_MFMA(0, E);
    F1_ALOAD(E);
    BARX();
    F1_BWRITE(O, 1); WAIT_LGKM0(); BARS();
    F1_BLOAD(O);
    F1_MFMA(1, O);
    F1_ALOAD(O);
    BARX();
  }
  F1_BWRITE(E, 0); WAIT_LGKM0(); BARS(); F1_MFMA(0, E); BARX();
  F1_BWRITE(O, 1); WAIT_LGKM0(); BARS(); F1_MFMA(1, O);

  // epilogue: silu(acc1)*acc3 -> Hb (C-layout) -> octet-major hO
  __syncthreads();
  int lr = (lane >> 4) << 2, lc = lane & 15;
  #pragma unroll
  for (int mi = 0; mi < 4; ++mi) {
    #pragma unroll
    for (int j = 0; j < 4; ++j) {
      int m = ((wr << 2) + mi) * 16 + lr + j;       // local row 0..127
      #pragma unroll
      for (int q = 0; q < 4; ++q) {
        int c = (wc << 6) + (q << 4) + lc;          // local col 0..127
        float a = acc1[mi][q][j];
        float gt = a / (1.f + __expf(-a));
        Hb[((size_t)(c >> 3) * BM + m) * 8 + (c & 7)] = f2bfs(gt * acc3[mi][q][j]);
      }
    }
  }
  __syncthreads();
  int co = tid >> 4, ml0 = (tid & 15) << 3;         // 16 col-octets x 16 row-groups
  size_t fo = (size_t)(n0 >> 3) + co;
  #pragma unroll
  for (int i = 0; i < 8; ++i) {
    int ml = ml0 + i;
    short8 vq = *(const short8*)(Hb + ((size_t)co * BM + ml) * 8);
    *(short8*)(hE + (fo * PAD_ + m0 + ml) * 8) = vq;
  }
}

// ---------------- ffn2: 128x128 tile, interleaved load-issue (r19) ----------------
__global__ __launch_bounds__(256, 3) void ffn2_kernel(
    const unsigned short* __restrict__ hO, const float* __restrict__ W2,
    const int* __restrict__ counts, const int* __restrict__ rowtok,
    const float* __restrict__ roww, float* __restrict__ y) {
  // grid 1536 = 8 xcd x (8 eg x 8 ni x 3 mb), mb fastest
  int bid = blockIdx.x;
  int r = bid & 7, u = bid >> 3;
  int mb = u % 3; int v = u / 3;
  int ni = v % 8; int eg = v / 8;
  int e = eg * 8 + r;
  int n0 = ni * BN;
  int m0 = mb * BM;
  int Me = min(counts[e], PAD_);
  if (m0 >= Me) return;

  const unsigned short* AO = hO + (size_t)e * PAD_ * DFF_;
  const float* Bw = W2 + (size_t)e * DFF_ * D_ + n0;

  __shared__ short Bs[2 * BK * BN];    // 2 x 8KB

  int tid = threadIdx.x;
  int lane = tid & 63;
  int wv = tid >> 6, wr = wv >> 1, wc = wv & 1;

  // B staging: all 256 threads; thread: 4 k-rows x 4 cols.
  int col4 = tid & 31;
  int krow0 = (tid >> 5) << 2;
  const float* qB = Bw + (size_t)krow0 * D_ + col4 * 4;
  int kseg = krow0 >> 3, khalf8 = ((krow0 >> 2) & 1) << 3;
  int boffc[4];
  #pragma unroll
  for (int cc = 0; cc < 4; ++cc) {
    int c = col4 * 4 + cc;
    boffc[cc] = ((c >> 4) << 10) + (SWZ((kseg << 4) + (c & 15)) << 4) + khalf8;
  }

  const unsigned short* qa =
      AO + (((size_t)(lane >> 4)) * PAD_ + m0 + (wr << 6) + (lane & 15)) * 8;

  short8 afE[4], afO[4];
  f32x4 fBE[4], fBO[4];
  f32x4 acc[4][4] = {};

#define F2_ALOAD(SET) do {                                               \
    _Pragma("unroll")                                                    \
    for (int mi = 0; mi < 4; ++mi)                                       \
      af##SET[mi] = *(const short8*)(qa + mi * 128);                     \
    qa += (size_t)4 * PAD_ * 8;                                          \
  } while (0)

#define F2_BLOAD(SET) do {                                               \
    _Pragma("unroll")                                                    \
    for (int j = 0; j < 4; ++j)                                          \
      fB##SET[j] = *(const f32x4*)(qB + (size_t)j * D_);                 \
    qB += (size_t)BK * D_;                                               \
  } while (0)

#define F2_BWRITE(SET, BUF) do {                                         \
    _Pragma("unroll")                                                    \
    for (int cc = 0; cc < 4; ++cc) {                                     \
      s16x4 w;                                                           \
      _Pragma("unroll")                                                  \
      for (int j = 0; j < 4; ++j) w[j] = f2bfs(fB##SET[j][cc]);          \
      *(s16x4*)((char*)Bs + (BUF)*8192 + boffc[cc]) = w;                 \
    }                                                                    \
  } while (0)

#define F2_MFMA(BUF, SET) do {                                           \
    int lsw = SWZ(lane) << 4;                                            \
    __builtin_amdgcn_s_setprio(1);                                       \
    _Pragma("unroll")                                                    \
    for (int q = 0; q < 4; ++q) {                                        \
      short8 bfr = *(const short8*)((char*)Bs + (BUF)*8192 + (((wc << 2) + q) << 10) + lsw); \
      _Pragma("unroll")                                                  \
      for (int mi = 0; mi < 4; ++mi)                                     \
        acc[mi][q] = __builtin_amdgcn_mfma_f32_16x16x32_bf16(af##SET[mi], bfr, acc[mi][q], 0, 0, 0); \
    }                                                                    \
    __builtin_amdgcn_s_setprio(0);                                       \
  } while (0)

  // 44 K-tiles, depth-2, interleaved issue
  F2_ALOAD(E); F2_BLOAD(E);
  F2_ALOAD(O); F2_BLOAD(O);
  for (int it = 0; it < 21; ++it) {
    F2_BWRITE(E, 0); WAIT_LGKM0(); BARS();
    F2_BLOAD(E);
    F2_MFMA(0, E);
    F2_ALOAD(E);
    BARX();
    F2_BWRITE(O, 1); WAIT_LGKM0(); BARS();
    F2_BLOAD(O);
    F2_MFMA(1, O);
    F2_ALOAD(O);
    BARX();
  }
  F2_BWRITE(E, 0); WAIT_LGKM0(); BARS(); F2_MFMA(0, E); BARX();
  F2_BWRITE(O, 1); WAIT_LGKM0(); BARS(); F2_MFMA(1, O);

  int lr = (lane >> 4) << 2, lc = lane & 15;
  #pragma unroll
  for (int mi = 0; mi < 4; ++mi) {
    #pragma unroll
    for (int j = 0; j < 4; ++j) {
      int m = m0 + ((wr << 2) + mi) * 16 + lr + j;
      if (m < Me) {
        int rw = e * PAD_ + m;
        int t = rowtok[rw];
        float w = roww[rw];
        int b = t >> 11, s = t & (S_ - 1);
        float* yp = y + (size_t)(s * B_ + b) * D_ + n0 + (wc << 6) + lc;
        #pragma unroll
        for (int q = 0; q < 4; ++q)
          atomicAdd(&yp[q << 4], w * acc[mi][q][j]);   // exactly 2 adds/elem
      }
    }
  }
}

extern "C" void kernel_launch(void* const* d_in, const int* in_sizes, int n_in,
                              void* d_out, int out_size, void* d_ws, size_t ws_size,
                              hipStream_t stream) {
  const float* x  = (const float*)d_in[0];
  const float* Wg = (const float*)d_in[1];
  const float* W1 = (const float*)d_in[2];
  const float* W3 = (const float*)d_in[3];
  const float* W2 = (const float*)d_in[4];
  float* y = (float*)d_out;
  float* laux = y + (size_t)S_ * B_ * D_;

  char* ws = (char*)d_ws;
  float* probs  = (float*)(ws + OFF_PROBS);
  int*   counts = (int*)  (ws + OFF_COUNTS);
  float* mesum  = (float*)(ws + OFF_MESUM);
  int*   rowtok = (int*)  (ws + OFF_ROWTOK);
  float* roww   = (float*)(ws + OFF_ROWW);
  unsigned short* xbufO = (unsigned short*)(ws + OFF_XBUF);
  unsigned short* hO    = (unsigned short*)(ws + OFF_H);

  hipMemsetAsync(d_out, 0, (size_t)out_size * sizeof(float), stream);
  hipMemsetAsync(counts, 0, 512, stream);

  gate_kernel<<<T_ / 8, 256, 0, stream>>>(x, Wg, probs, counts, rowtok, roww, xbufO);
  me_kernel<<<E_, 256, 0, stream>>>(probs, mesum);
  finalize_kernel<<<1, 64, 0, stream>>>(counts, mesum, laux);
  ffn1_kernel<<<8 * 8 * 11 * 3, 256, 0, stream>>>(xbufO, W1, W3, counts, hO);
  ffn2_kernel<<<8 * 8 * 8 * 3, 256, 0, stream>>>(hO, W2, counts, rowtok, roww, y);
}

// Round 22
// 566.239 us; speedup vs baseline: 1.1447x; 1.0241x over previous
//
#include <hip/hip_runtime.h>
#include <hip/hip_bf16.h>

// MoE E=64, top-2, T=8192, D=1024, DFF=1408. Round 22 (base = r21, single
// change: ffn2 atomic y-epilogue -> compact bf16 store + combine kernel):
//  - ffn2 stores raw acc rows to eoO[e][m][D] (bf16, coalesced, no atomics;
//    eoO aliases the dead xbufO region). gate records per-token (e,slot,w).
//  - combine_kernel: y[t] = w1*eo1 + w2*eo2, one coalesced write/elem.
//    Kills 64M scattered f32 atomics (~0.5GB RMW) + the 33MB y memset.
//  - ffn1 and everything else = r21.

#define S_ 2048
#define B_ 4
#define D_ 1024
#define DFF_ 1408
#define E_ 64
#define T_ 8192
#define KTOP_ 2
#define NPAIR_ (T_*KTOP_)
#define PAD_ 384
#define ROWS_ (E_*PAD_)

#define BM 128
#define BN 128
#define BK 32

typedef __attribute__((ext_vector_type(8))) short short8;
typedef __attribute__((ext_vector_type(4))) short s16x4;
typedef __attribute__((ext_vector_type(4))) float f32x4;
typedef __attribute__((ext_vector_type(4))) unsigned short us4;

// ---------------- workspace layout (bytes) ----------------
constexpr size_t OFF_PROBS  = 0;                                  // T*E f32
constexpr size_t OFF_COUNTS = OFF_PROBS + (size_t)T_*E_*4;        // 64 int (+pad)
constexpr size_t OFF_MESUM  = OFF_COUNTS + 512;                   // 64 f32
constexpr size_t OFF_PAIRE  = OFF_MESUM + 256;                    // NPAIR int
constexpr size_t OFF_PAIRM  = OFF_PAIRE + (size_t)NPAIR_*4;       // NPAIR int
constexpr size_t OFF_PAIRW  = OFF_PAIRM + (size_t)NPAIR_*4;       // NPAIR f32
constexpr size_t OFF_XBUF   = OFF_PAIRW + (size_t)NPAIR_*4;       // ROWS*D bf16 (xbufO, later eoO)
constexpr size_t OFF_H      = OFF_XBUF + (size_t)ROWS_*D_*2;      // ROWS*DFF bf16

__device__ __forceinline__ short f2bfs(float f) {
  union { __hip_bfloat16 h; short s; } u;
  u.h = __float2bfloat16(f);
  return u.s;
}
__device__ __forceinline__ float bf2f(unsigned short u) {
  unsigned v = ((unsigned)u) << 16;
  return __uint_as_float(v);
}

// granule XOR swizzle for B staging (conflict-free frag reads)
__device__ __forceinline__ int SWZ(int g) { return g ^ (((g >> 4) & 3) << 1); }

#define BARS() do {                                  \
    __builtin_amdgcn_sched_barrier(0);               \
    __builtin_amdgcn_s_barrier();                    \
    __builtin_amdgcn_sched_barrier(0);               \
  } while (0)
#define BARX() __builtin_amdgcn_s_barrier()
#define WAIT_LGKM0() asm volatile("s_waitcnt lgkmcnt(0)" ::: "memory")

// ---------------- gate + fused scatter ----------------
__device__ __forceinline__ float softmax64(float acc, int lane) {
  float m = acc;
  for (int o = 32; o; o >>= 1) m = fmaxf(m, __shfl_xor(m, o));
  float p = expf(acc - m);
  float s = p;
  for (int o = 32; o; o >>= 1) s += __shfl_xor(s, o);
  return p / s;
}

__global__ __launch_bounds__(256) void gate_kernel(
    const float* __restrict__ x, const float* __restrict__ Wg,
    float* __restrict__ probs, int* __restrict__ counts,
    int* __restrict__ pairE, int* __restrict__ pairM, float* __restrict__ pairW,
    unsigned short* __restrict__ xbufO) {
  int t0 = blockIdx.x * 8;
  int tid = threadIdx.x;
  int lane = tid & 63, wv = tid >> 6;
  __shared__ float tk[8][D_];
  __shared__ int sE[8][2];
  __shared__ int sM[8][2];
  for (int u = tid; u < 8 * (D_ / 4); u += 256) {
    int r = u >> 8, c4 = u & 255;
    int t = t0 + r;
    int b = t >> 11, s = t & (S_ - 1);
    ((float4*)tk[r])[c4] = ((const float4*)(x + (size_t)(s * B_ + b) * D_))[c4];
  }
  __syncthreads();
  const float* tkA = tk[2 * wv];
  const float* tkB = tk[2 * wv + 1];
  float acc0 = 0.f, acc1 = 0.f;
  #pragma unroll 8
  for (int d = 0; d < D_; ++d) {
    float w = Wg[(size_t)d * E_ + lane];
    acc0 += tkA[d] * w;
    acc1 += tkB[d] * w;
  }
  #pragma unroll
  for (int half = 0; half < 2; ++half) {
    float p = softmax64(half ? acc1 : acc0, lane);
    int tkn = 2 * wv + half;
    int t = t0 + tkn;
    probs[(size_t)t * E_ + lane] = p;
    float v1 = p; int i1 = lane;
    for (int o = 32; o; o >>= 1) {
      float ov = __shfl_xor(v1, o); int oi = __shfl_xor(i1, o);
      if (ov > v1 || (ov == v1 && oi < i1)) { v1 = ov; i1 = oi; }
    }
    float v2 = (lane == i1) ? -1.f : p; int i2 = lane;
    for (int o = 32; o; o >>= 1) {
      float ov = __shfl_xor(v2, o); int oi = __shfl_xor(i2, o);
      if (ov > v2 || (ov == v2 && oi < i2)) { v2 = ov; i2 = oi; }
    }
    if (lane == 0) {
      float wsum = v1 + v2;
      int s1 = atomicAdd(&counts[i1], 1);
      int s2 = atomicAdd(&counts[i2], 1);
      int m1 = (s1 < PAD_) ? s1 : -1;
      int m2 = (s2 < PAD_) ? s2 : -1;
      pairE[2 * t]     = i1; pairM[2 * t]     = m1; pairW[2 * t]     = v1 / wsum;
      pairE[2 * t + 1] = i2; pairM[2 * t + 1] = m2; pairW[2 * t + 1] = v2 / wsum;
      sE[tkn][0] = i1; sM[tkn][0] = m1;
      sE[tkn][1] = i2; sM[tkn][1] = m2;
    }
  }
  __syncthreads();
  // fused scatter: 16 (token,expert) rows; half-block per row, granule/thread
  int hh = tid >> 7, t7 = tid & 127;
  #pragma unroll
  for (int pp = 0; pp < 8; ++pp) {
    int pr = 2 * pp + hh;
    int tkn = pr >> 1, j = pr & 1;
    int e = sE[tkn][j];
    int m = sM[tkn][j];
    if (m >= 0) {
      const float* src = tk[tkn] + t7 * 8;
      short8 g;
      #pragma unroll
      for (int k = 0; k < 8; ++k) g[k] = f2bfs(src[k]);
      *(short8*)(xbufO + (size_t)e * D_ * PAD_ + ((size_t)t7 * PAD_ + m) * 8) = g;
    }
  }
}

// ---------------- me reduce ----------------
__global__ __launch_bounds__(256) void me_kernel(const float* __restrict__ probs,
                                                 float* __restrict__ mesum) {
  int e = blockIdx.x, tid = threadIdx.x;
  float a = 0.f;
  for (int t = tid; t < T_; t += 256) a += probs[(size_t)t * E_ + e];
  __shared__ float red[256];
  red[tid] = a; __syncthreads();
  for (int s = 128; s; s >>= 1) {
    if (tid < s) red[tid] += red[tid + s];
    __syncthreads();
  }
  if (tid == 0) mesum[e] = red[0];
}

// ---------------- finalize l_aux ----------------
__global__ __launch_bounds__(64) void finalize_kernel(
    const int* __restrict__ counts, const float* __restrict__ mesum,
    float* __restrict__ laux_out) {
  int lane = threadIdx.x;
  float contrib = (mesum[lane] / (float)T_) * ((float)counts[lane] / (float)(T_ * KTOP_));
  for (int o = 32; o; o >>= 1) contrib += __shfl_xor(contrib, o);
  if (lane == 0) laux_out[0] = (float)E_ * contrib;
}

// ---------------- ffn1: 128x128 tile, interleaved load-issue (r19) ----------------
__global__ __launch_bounds__(256, 2) void ffn1_kernel(
    const unsigned short* __restrict__ xbufO, const float* __restrict__ W1,
    const float* __restrict__ W3, const int* __restrict__ counts,
    unsigned short* __restrict__ hO) {
  // grid 2112 = 8 xcd x (8 eg x 11 ni x 3 mb), mb fastest (W L2 sharing)
  int bid = blockIdx.x;
  int r = bid & 7, u = bid >> 3;
  int mb = u % 3; int v = u / 3;
  int ni = v % 11; int eg = v / 11;
  int e = eg * 8 + r;
  int n0 = ni * BN;
  int m0 = mb * BM;
  int Me = min(counts[e], PAD_);
  if (m0 >= Me) return;                  // block-granular pad skip

  const unsigned short* AO = xbufO + (size_t)e * D_ * PAD_;
  const float* B1p = W1 + (size_t)e * D_ * DFF_ + n0;
  const float* B3p = W3 + (size_t)e * D_ * DFF_ + n0;
  unsigned short* hE = hO + (size_t)e * PAD_ * DFF_;

  __shared__ short B1s[2 * BK * BN];   // 2 x 8KB
  __shared__ short B3s[2 * BK * BN];   // 2 x 8KB
  __shared__ short Hb[BM * BN];        // 32KB epilogue transpose bounce

  int tid = threadIdx.x;
  int lane = tid & 63;
  int wv = tid >> 6, wr = wv >> 1, wc = wv & 1;

  // B staging: tid<128 -> W1, >=128 -> W3. Thread: 8 k-rows x 4 cols.
  int msel = tid >> 7;
  int t7 = tid & 127;
  int col4 = t7 & 31;
  int krow0 = (t7 >> 5) << 3;
  const float* qB = (msel ? B3p : B1p) + (size_t)krow0 * DFF_ + col4 * 4;
  char* Bdst = (char*)(msel ? B3s : B1s);
  int kseg = krow0 >> 3;
  int boffc[4];
  #pragma unroll
  for (int cc = 0; cc < 4; ++cc) {
    int c = col4 * 4 + cc;
    boffc[cc] = ((c >> 4) << 10) + (SWZ((kseg << 4) + (c & 15)) << 4);
  }

  // A-direct: frag f=wr*4+mi; lane: row m0+f*16+(lane&15), octet 4t+(lane>>4)
  const unsigned short* qa =
      AO + (((size_t)(lane >> 4)) * PAD_ + m0 + (wr << 6) + (lane & 15)) * 8;

  short8 afE[4], afO[4];
  f32x4 fBE[8], fBO[8];
  f32x4 acc1[4][4] = {};
  f32x4 acc3[4][4] = {};

#define F1_ALOAD(SET) do {                                               \
    _Pragma("unroll")                                                    \
    for (int mi = 0; mi < 4; ++mi)                                       \
      af##SET[mi] = *(const short8*)(qa + mi * 128);                     \
    qa += (size_t)4 * PAD_ * 8;                                          \
  } while (0)

#define F1_BLOAD(SET) do {                                               \
    _Pragma("unroll")                                                    \
    for (int j = 0; j < 8; ++j)                                          \
      fB##SET[j] = *(const f32x4*)(qB + (size_t)j * DFF_);               \
    qB += (size_t)BK * DFF_;                                             \
  } while (0)

#define F1_BWRITE(SET, BUF) do {                                         \
    _Pragma("unroll")                                                    \
    for (int cc = 0; cc < 4; ++cc) {                                     \
      short8 w;                                                          \
      _Pragma("unroll")                                                  \
      for (int j = 0; j < 8; ++j) w[j] = f2bfs(fB##SET[j][cc]);          \
      *(short8*)(Bdst + (BUF)*8192 + boffc[cc]) = w;                     \
    }                                                                    \
  } while (0)

#define F1_MFMA(BUF, SET) do {                                           \
    int lsw = SWZ(lane) << 4;                                            \
    __builtin_amdgcn_s_setprio(1);                                       \
    _Pragma("unroll")                                                    \
    for (int q = 0; q < 4; ++q) {                                        \
      short8 bf1 = *(const short8*)((char*)B1s + (BUF)*8192 + (((wc << 2) + q) << 10) + lsw); \
      short8 bf3 = *(const short8*)((char*)B3s + (BUF)*8192 + (((wc << 2) + q) << 10) + lsw); \
      _Pragma("unroll")                                                  \
      for (int mi = 0; mi < 4; ++mi) {                                   \
        acc1[mi][q] = __builtin_amdgcn_mfma_f32_16x16x32_bf16(af##SET[mi], bf1, acc1[mi][q], 0, 0, 0); \
        acc3[mi][q] = __builtin_amdgcn_mfma_f32_16x16x32_bf16(af##SET[mi], bf3, acc3[mi][q], 0, 0, 0); \
      }                                                                  \
    }                                                                    \
    __builtin_amdgcn_s_setprio(0);                                       \
  } while (0)

  // 32 K-tiles, depth-2, interleaved issue (r19)
  F1_ALOAD(E); F1_BLOAD(E);      // t0
  F1_ALOAD(O); F1_BLOAD(O);      // t1
  for (int it = 0; it < 15; ++it) {
    F1_BWRITE(E, 0); WAIT_LGKM0(); BARS();
    F1_BLOAD(E);
    F1_MFMA(0, E);
    F1_ALOAD(E);
    BARX();
    F1_BWRITE(O, 1); WAIT_LGKM0(); BARS();
    F1_BLOAD(O);
    F1_MFMA(1, O);
    F1_ALOAD(O);
    BARX();
  }
  F1_BWRITE(E, 0); WAIT_LGKM0(); BARS(); F1_MFMA(0, E); BARX();
  F1_BWRITE(O, 1); WAIT_LGKM0(); BARS(); F1_MFMA(1, O);

  // epilogue: silu(acc1)*acc3 -> Hb (C-layout) -> octet-major hO
  __syncthreads();
  int lr = (lane >> 4) << 2, lc = lane & 15;
  #pragma unroll
  for (int mi = 0; mi < 4; ++mi) {
    #pragma unroll
    for (int j = 0; j < 4; ++j) {
      int m = ((wr << 2) + mi) * 16 + lr + j;       // local row 0..127
      #pragma unroll
      for (int q = 0; q < 4; ++q) {
        int c = (wc << 6) + (q << 4) + lc;          // local col 0..127
        float a = acc1[mi][q][j];
        float gt = a / (1.f + __expf(-a));
        Hb[((size_t)(c >> 3) * BM + m) * 8 + (c & 7)] = f2bfs(gt * acc3[mi][q][j]);
      }
    }
  }
  __syncthreads();
  int co = tid >> 4, ml0 = (tid & 15) << 3;         // 16 col-octets x 16 row-groups
  size_t fo = (size_t)(n0 >> 3) + co;
  #pragma unroll
  for (int i = 0; i < 8; ++i) {
    int ml = ml0 + i;
    short8 vq = *(const short8*)(Hb + ((size_t)co * BM + ml) * 8);
    *(short8*)(hE + (fo * PAD_ + m0 + ml) * 8) = vq;
  }
}

// ---------------- ffn2: 128x128 tile, compact bf16 eo store ----------------
__global__ __launch_bounds__(256, 3) void ffn2_kernel(
    const unsigned short* __restrict__ hO, const float* __restrict__ W2,
    const int* __restrict__ counts, unsigned short* __restrict__ eoO) {
  // grid 1536 = 8 xcd x (8 eg x 8 ni x 3 mb), mb fastest
  int bid = blockIdx.x;
  int r = bid & 7, u = bid >> 3;
  int mb = u % 3; int v = u / 3;
  int ni = v % 8; int eg = v / 8;
  int e = eg * 8 + r;
  int n0 = ni * BN;
  int m0 = mb * BM;
  int Me = min(counts[e], PAD_);
  if (m0 >= Me) return;

  const unsigned short* AO = hO + (size_t)e * PAD_ * DFF_;
  const float* Bw = W2 + (size_t)e * DFF_ * D_ + n0;

  __shared__ short Bs[2 * BK * BN];    // 2 x 8KB

  int tid = threadIdx.x;
  int lane = tid & 63;
  int wv = tid >> 6, wr = wv >> 1, wc = wv & 1;

  // B staging: all 256 threads; thread: 4 k-rows x 4 cols.
  int col4 = tid & 31;
  int krow0 = (tid >> 5) << 2;
  const float* qB = Bw + (size_t)krow0 * D_ + col4 * 4;
  int kseg = krow0 >> 3, khalf8 = ((krow0 >> 2) & 1) << 3;
  int boffc[4];
  #pragma unroll
  for (int cc = 0; cc < 4; ++cc) {
    int c = col4 * 4 + cc;
    boffc[cc] = ((c >> 4) << 10) + (SWZ((kseg << 4) + (c & 15)) << 4) + khalf8;
  }

  const unsigned short* qa =
      AO + (((size_t)(lane >> 4)) * PAD_ + m0 + (wr << 6) + (lane & 15)) * 8;

  short8 afE[4], afO[4];
  f32x4 fBE[4], fBO[4];
  f32x4 acc[4][4] = {};

#define F2_ALOAD(SET) do {                                               \
    _Pragma("unroll")                                                    \
    for (int mi = 0; mi < 4; ++mi)                                       \
      af##SET[mi] = *(const short8*)(qa + mi * 128);                     \
    qa += (size_t)4 * PAD_ * 8;                                          \
  } while (0)

#define F2_BLOAD(SET) do {                                               \
    _Pragma("unroll")                                                    \
    for (int j = 0; j < 4; ++j)                                          \
      fB##SET[j] = *(const f32x4*)(qB + (size_t)j * D_);                 \
    qB += (size_t)BK * D_;                                               \
  } while (0)

#define F2_BWRITE(SET, BUF) do {                                         \
    _Pragma("unroll")                                                    \
    for (int cc = 0; cc < 4; ++cc) {                                     \
      s16x4 w;                                                           \
      _Pragma("unroll")                                                  \
      for (int j = 0; j < 4; ++j) w[j] = f2bfs(fB##SET[j][cc]);          \
      *(s16x4*)((char*)Bs + (BUF)*8192 + boffc[cc]) = w;                 \
    }                                                                    \
  } while (0)

#define F2_MFMA(BUF, SET) do {                                           \
    int lsw = SWZ(lane) << 4;                                            \
    __builtin_amdgcn_s_setprio(1);                                       \
    _Pragma("unroll")                                                    \
    for (int q = 0; q < 4; ++q) {                                        \
      short8 bfr = *(const short8*)((char*)Bs + (BUF)*8192 + (((wc << 2) + q) << 10) + lsw); \
      _Pragma("unroll")                                                  \
      for (int mi = 0; mi < 4; ++mi)                                     \
        acc[mi][q] = __builtin_amdgcn_mfma_f32_16x16x32_bf16(af##SET[mi], bfr, acc[mi][q], 0, 0, 0); \
    }                                                                    \
    __builtin_amdgcn_s_setprio(0);                                       \
  } while (0)

  // 44 K-tiles, depth-2, interleaved issue
  F2_ALOAD(E); F2_BLOAD(E);
  F2_ALOAD(O); F2_BLOAD(O);
  for (int it = 0; it < 21; ++it) {
    F2_BWRITE(E, 0); WAIT_LGKM0(); BARS();
    F2_BLOAD(E);
    F2_MFMA(0, E);
    F2_ALOAD(E);
    BARX();
    F2_BWRITE(O, 1); WAIT_LGKM0(); BARS();
    F2_BLOAD(O);
    F2_MFMA(1, O);
    F2_ALOAD(O);
    BARX();
  }
  F2_BWRITE(E, 0); WAIT_LGKM0(); BARS(); F2_MFMA(0, E); BARX();
  F2_BWRITE(O, 1); WAIT_LGKM0(); BARS(); F2_MFMA(1, O);

  // epilogue: coalesced bf16 store of raw acc to eoO[e][m][D]
  unsigned short* eoE = eoO + (size_t)e * PAD_ * D_;
  int lr = (lane >> 4) << 2, lc = lane & 15;
  #pragma unroll
  for (int mi = 0; mi < 4; ++mi) {
    #pragma unroll
    for (int j = 0; j < 4; ++j) {
      int m = m0 + ((wr << 2) + mi) * 16 + lr + j;
      if (m < Me) {
        unsigned short* op = eoE + (size_t)m * D_ + n0 + (wc << 6) + lc;
        #pragma unroll
        for (int q = 0; q < 4; ++q)
          op[q << 4] = (unsigned short)f2bfs(acc[mi][q][j]);
      }
    }
  }
}

// ---------------- combine: y[t] = w1*eo1 + w2*eo2 ----------------
__global__ __launch_bounds__(256) void combine_kernel(
    const unsigned short* __restrict__ eoO, const int* __restrict__ pairE,
    const int* __restrict__ pairM, const float* __restrict__ pairW,
    float* __restrict__ y) {
  int t = blockIdx.x * 4 + (threadIdx.x >> 6);
  int lane = threadIdx.x & 63;
  int e1 = pairE[2 * t], m1 = pairM[2 * t];
  int e2 = pairE[2 * t + 1], m2 = pairM[2 * t + 1];
  float w1 = pairW[2 * t], w2 = pairW[2 * t + 1];
  float out[16];
  #pragma unroll
  for (int i = 0; i < 16; ++i) out[i] = 0.f;
  if (m1 >= 0) {
    const unsigned short* rp = eoO + ((size_t)e1 * PAD_ + m1) * D_ + lane * 16;
    short8 a = *(const short8*)rp, b = *(const short8*)(rp + 8);
    #pragma unroll
    for (int i = 0; i < 8; ++i) {
      out[i]     += w1 * bf2f((unsigned short)a[i]);
      out[8 + i] += w1 * bf2f((unsigned short)b[i]);
    }
  }
  if (m2 >= 0) {
    const unsigned short* rp = eoO + ((size_t)e2 * PAD_ + m2) * D_ + lane * 16;
    short8 a = *(const short8*)rp, b = *(const short8*)(rp + 8);
    #pragma unroll
    for (int i = 0; i < 8; ++i) {
      out[i]     += w2 * bf2f((unsigned short)a[i]);
      out[8 + i] += w2 * bf2f((unsigned short)b[i]);
    }
  }
  int b = t >> 11, s = t & (S_ - 1);
  float* yp = y + (size_t)(s * B_ + b) * D_ + lane * 16;
  #pragma unroll
  for (int v = 0; v < 4; ++v) {
    float4 o4 = make_float4(out[v * 4], out[v * 4 + 1], out[v * 4 + 2], out[v * 4 + 3]);
    *(float4*)(yp + v * 4) = o4;
  }
}

extern "C" void kernel_launch(void* const* d_in, const int* in_sizes, int n_in,
                              void* d_out, int out_size, void* d_ws, size_t ws_size,
                              hipStream_t stream) {
  const float* x  = (const float*)d_in[0];
  const float* Wg = (const float*)d_in[1];
  const float* W1 = (const float*)d_in[2];
  const float* W3 = (const float*)d_in[3];
  const float* W2 = (const float*)d_in[4];
  float* y = (float*)d_out;
  float* laux = y + (size_t)S_ * B_ * D_;

  char* ws = (char*)d_ws;
  float* probs  = (float*)(ws + OFF_PROBS);
  int*   counts = (int*)  (ws + OFF_COUNTS);
  float* mesum  = (float*)(ws + OFF_MESUM);
  int*   pairE  = (int*)  (ws + OFF_PAIRE);
  int*   pairM  = (int*)  (ws + OFF_PAIRM);
  float* pairW  = (float*)(ws + OFF_PAIRW);
  unsigned short* xbufO = (unsigned short*)(ws + OFF_XBUF);  // also eoO
  unsigned short* hO    = (unsigned short*)(ws + OFF_H);

  hipMemsetAsync(counts, 0, 512, stream);

  gate_kernel<<<T_ / 8, 256, 0, stream>>>(x, Wg, probs, counts, pairE, pairM, pairW, xbufO);
  me_kernel<<<E_, 256, 0, stream>>>(probs, mesum);
  finalize_kernel<<<1, 64, 0, stream>>>(counts, mesum, laux);
  ffn1_kernel<<<8 * 8 * 11 * 3, 256, 0, stream>>>(xbufO, W1, W3, counts, hO);
  ffn2_kernel<<<8 * 8 * 8 * 3, 256, 0, stream>>>(hO, W2, counts, xbufO);  // eoO aliases xbufO
  combine_kernel<<<T_ / 4, 256, 0, stream>>>(xbufO, pairE, pairM, pairW, y);
}

// Round 23
// 566.152 us; speedup vs baseline: 1.1448x; 1.0002x over previous
//
#include <hip/hip_runtime.h>
#include <hip/hip_bf16.h>

// MoE E=64, top-2, T=8192, D=1024, DFF=1408. Round 23 (base = r22, single
// change: ffn1 LDS halved by aliasing the epilogue Hb bounce onto the dead
// B double-buffers):
//  - Hb (32KB) is only touched after the K-loop's last LDS read; one 32KB
//    shared arena holds {B1s,B3s} during the loop and Hb in the epilogue
//    (separated by __syncthreads). LDS 64KB -> 32KB: 2 -> 4 blocks/CU.
//  - 4 independent barrier groups/CU cover each other's stage stalls.
//  - Everything else = r22 (fused gate/scatter, A-direct, 128x128 tiles,
//    compact eo + combine).

#define S_ 2048
#define B_ 4
#define D_ 1024
#define DFF_ 1408
#define E_ 64
#define T_ 8192
#define KTOP_ 2
#define NPAIR_ (T_*KTOP_)
#define PAD_ 384
#define ROWS_ (E_*PAD_)

#define BM 128
#define BN 128
#define BK 32

typedef __attribute__((ext_vector_type(8))) short short8;
typedef __attribute__((ext_vector_type(4))) short s16x4;
typedef __attribute__((ext_vector_type(4))) float f32x4;
typedef __attribute__((ext_vector_type(4))) unsigned short us4;

// ---------------- workspace layout (bytes) ----------------
constexpr size_t OFF_PROBS  = 0;                                  // T*E f32
constexpr size_t OFF_COUNTS = OFF_PROBS + (size_t)T_*E_*4;        // 64 int (+pad)
constexpr size_t OFF_MESUM  = OFF_COUNTS + 512;                   // 64 f32
constexpr size_t OFF_PAIRE  = OFF_MESUM + 256;                    // NPAIR int
constexpr size_t OFF_PAIRM  = OFF_PAIRE + (size_t)NPAIR_*4;       // NPAIR int
constexpr size_t OFF_PAIRW  = OFF_PAIRM + (size_t)NPAIR_*4;       // NPAIR f32
constexpr size_t OFF_XBUF   = OFF_PAIRW + (size_t)NPAIR_*4;       // ROWS*D bf16 (xbufO, later eoO)
constexpr size_t OFF_H      = OFF_XBUF + (size_t)ROWS_*D_*2;      // ROWS*DFF bf16

__device__ __forceinline__ short f2bfs(float f) {
  union { __hip_bfloat16 h; short s; } u;
  u.h = __float2bfloat16(f);
  return u.s;
}
__device__ __forceinline__ float bf2f(unsigned short u) {
  unsigned v = ((unsigned)u) << 16;
  return __uint_as_float(v);
}

// granule XOR swizzle for B staging (conflict-free frag reads)
__device__ __forceinline__ int SWZ(int g) { return g ^ (((g >> 4) & 3) << 1); }

#define BARS() do {                                  \
    __builtin_amdgcn_sched_barrier(0);               \
    __builtin_amdgcn_s_barrier();                    \
    __builtin_amdgcn_sched_barrier(0);               \
  } while (0)
#define BARX() __builtin_amdgcn_s_barrier()
#define WAIT_LGKM0() asm volatile("s_waitcnt lgkmcnt(0)" ::: "memory")

// ---------------- gate + fused scatter ----------------
__device__ __forceinline__ float softmax64(float acc, int lane) {
  float m = acc;
  for (int o = 32; o; o >>= 1) m = fmaxf(m, __shfl_xor(m, o));
  float p = expf(acc - m);
  float s = p;
  for (int o = 32; o; o >>= 1) s += __shfl_xor(s, o);
  return p / s;
}

__global__ __launch_bounds__(256) void gate_kernel(
    const float* __restrict__ x, const float* __restrict__ Wg,
    float* __restrict__ probs, int* __restrict__ counts,
    int* __restrict__ pairE, int* __restrict__ pairM, float* __restrict__ pairW,
    unsigned short* __restrict__ xbufO) {
  int t0 = blockIdx.x * 8;
  int tid = threadIdx.x;
  int lane = tid & 63, wv = tid >> 6;
  __shared__ float tk[8][D_];
  __shared__ int sE[8][2];
  __shared__ int sM[8][2];
  for (int u = tid; u < 8 * (D_ / 4); u += 256) {
    int r = u >> 8, c4 = u & 255;
    int t = t0 + r;
    int b = t >> 11, s = t & (S_ - 1);
    ((float4*)tk[r])[c4] = ((const float4*)(x + (size_t)(s * B_ + b) * D_))[c4];
  }
  __syncthreads();
  const float* tkA = tk[2 * wv];
  const float* tkB = tk[2 * wv + 1];
  float acc0 = 0.f, acc1 = 0.f;
  #pragma unroll 8
  for (int d = 0; d < D_; ++d) {
    float w = Wg[(size_t)d * E_ + lane];
    acc0 += tkA[d] * w;
    acc1 += tkB[d] * w;
  }
  #pragma unroll
  for (int half = 0; half < 2; ++half) {
    float p = softmax64(half ? acc1 : acc0, lane);
    int tkn = 2 * wv + half;
    int t = t0 + tkn;
    probs[(size_t)t * E_ + lane] = p;
    float v1 = p; int i1 = lane;
    for (int o = 32; o; o >>= 1) {
      float ov = __shfl_xor(v1, o); int oi = __shfl_xor(i1, o);
      if (ov > v1 || (ov == v1 && oi < i1)) { v1 = ov; i1 = oi; }
    }
    float v2 = (lane == i1) ? -1.f : p; int i2 = lane;
    for (int o = 32; o; o >>= 1) {
      float ov = __shfl_xor(v2, o); int oi = __shfl_xor(i2, o);
      if (ov > v2 || (ov == v2 && oi < i2)) { v2 = ov; i2 = oi; }
    }
    if (lane == 0) {
      float wsum = v1 + v2;
      int s1 = atomicAdd(&counts[i1], 1);
      int s2 = atomicAdd(&counts[i2], 1);
      int m1 = (s1 < PAD_) ? s1 : -1;
      int m2 = (s2 < PAD_) ? s2 : -1;
      pairE[2 * t]     = i1; pairM[2 * t]     = m1; pairW[2 * t]     = v1 / wsum;
      pairE[2 * t + 1] = i2; pairM[2 * t + 1] = m2; pairW[2 * t + 1] = v2 / wsum;
      sE[tkn][0] = i1; sM[tkn][0] = m1;
      sE[tkn][1] = i2; sM[tkn][1] = m2;
    }
  }
  __syncthreads();
  // fused scatter: 16 (token,expert) rows; half-block per row, granule/thread
  int hh = tid >> 7, t7 = tid & 127;
  #pragma unroll
  for (int pp = 0; pp < 8; ++pp) {
    int pr = 2 * pp + hh;
    int tkn = pr >> 1, j = pr & 1;
    int e = sE[tkn][j];
    int m = sM[tkn][j];
    if (m >= 0) {
      const float* src = tk[tkn] + t7 * 8;
      short8 g;
      #pragma unroll
      for (int k = 0; k < 8; ++k) g[k] = f2bfs(src[k]);
      *(short8*)(xbufO + (size_t)e * D_ * PAD_ + ((size_t)t7 * PAD_ + m) * 8) = g;
    }
  }
}

// ---------------- me reduce ----------------
__global__ __launch_bounds__(256) void me_kernel(const float* __restrict__ probs,
                                                 float* __restrict__ mesum) {
  int e = blockIdx.x, tid = threadIdx.x;
  float a = 0.f;
  for (int t = tid; t < T_; t += 256) a += probs[(size_t)t * E_ + e];
  __shared__ float red[256];
  red[tid] = a; __syncthreads();
  for (int s = 128; s; s >>= 1) {
    if (tid < s) red[tid] += red[tid + s];
    __syncthreads();
  }
  if (tid == 0) mesum[e] = red[0];
}

// ---------------- finalize l_aux ----------------
__global__ __launch_bounds__(64) void finalize_kernel(
    const int* __restrict__ counts, const float* __restrict__ mesum,
    float* __restrict__ laux_out) {
  int lane = threadIdx.x;
  float contrib = (mesum[lane] / (float)T_) * ((float)counts[lane] / (float)(T_ * KTOP_));
  for (int o = 32; o; o >>= 1) contrib += __shfl_xor(contrib, o);
  if (lane == 0) laux_out[0] = (float)E_ * contrib;
}

// ---------------- ffn1: 128x128 tile, 32KB aliased LDS ----------------
__global__ __launch_bounds__(256, 2) void ffn1_kernel(
    const unsigned short* __restrict__ xbufO, const float* __restrict__ W1,
    const float* __restrict__ W3, const int* __restrict__ counts,
    unsigned short* __restrict__ hO) {
  // grid 2112 = 8 xcd x (8 eg x 11 ni x 3 mb), mb fastest (W L2 sharing)
  int bid = blockIdx.x;
  int r = bid & 7, u = bid >> 3;
  int mb = u % 3; int v = u / 3;
  int ni = v % 11; int eg = v / 11;
  int e = eg * 8 + r;
  int n0 = ni * BN;
  int m0 = mb * BM;
  int Me = min(counts[e], PAD_);
  if (m0 >= Me) return;                  // block-granular pad skip

  const unsigned short* AO = xbufO + (size_t)e * D_ * PAD_;
  const float* B1p = W1 + (size_t)e * D_ * DFF_ + n0;
  const float* B3p = W3 + (size_t)e * D_ * DFF_ + n0;
  unsigned short* hE = hO + (size_t)e * PAD_ * DFF_;

  // 32KB arena: K-loop = {B1s: 0..16K, B3s: 16K..32K}; epilogue = Hb (32KB)
  __shared__ char smem[32768];
  short* B1s = (short*)smem;
  short* B3s = (short*)(smem + 16384);
  short* Hb  = (short*)smem;

  int tid = threadIdx.x;
  int lane = tid & 63;
  int wv = tid >> 6, wr = wv >> 1, wc = wv & 1;

  // B staging: tid<128 -> W1, >=128 -> W3. Thread: 8 k-rows x 4 cols.
  int msel = tid >> 7;
  int t7 = tid & 127;
  int col4 = t7 & 31;
  int krow0 = (t7 >> 5) << 3;
  const float* qB = (msel ? B3p : B1p) + (size_t)krow0 * DFF_ + col4 * 4;
  char* Bdst = (char*)(msel ? B3s : B1s);
  int kseg = krow0 >> 3;
  int boffc[4];
  #pragma unroll
  for (int cc = 0; cc < 4; ++cc) {
    int c = col4 * 4 + cc;
    boffc[cc] = ((c >> 4) << 10) + (SWZ((kseg << 4) + (c & 15)) << 4);
  }

  // A-direct: frag f=wr*4+mi; lane: row m0+f*16+(lane&15), octet 4t+(lane>>4)
  const unsigned short* qa =
      AO + (((size_t)(lane >> 4)) * PAD_ + m0 + (wr << 6) + (lane & 15)) * 8;

  short8 afE[4], afO[4];
  f32x4 fBE[8], fBO[8];
  f32x4 acc1[4][4] = {};
  f32x4 acc3[4][4] = {};

#define F1_ALOAD(SET) do {                                               \
    _Pragma("unroll")                                                    \
    for (int mi = 0; mi < 4; ++mi)                                       \
      af##SET[mi] = *(const short8*)(qa + mi * 128);                     \
    qa += (size_t)4 * PAD_ * 8;                                          \
  } while (0)

#define F1_BLOAD(SET) do {                                               \
    _Pragma("unroll")                                                    \
    for (int j = 0; j < 8; ++j)                                          \
      fB##SET[j] = *(const f32x4*)(qB + (size_t)j * DFF_);               \
    qB += (size_t)BK * DFF_;                                             \
  } while (0)

#define F1_BWRITE(SET, BUF) do {                                         \
    _Pragma("unroll")                                                    \
    for (int cc = 0; cc < 4; ++cc) {                                     \
      short8 w;                                                          \
      _Pragma("unroll")                                                  \
      for (int j = 0; j < 8; ++j) w[j] = f2bfs(fB##SET[j][cc]);          \
      *(short8*)(Bdst + (BUF)*8192 + boffc[cc]) = w;                     \
    }                                                                    \
  } while (0)

#define F1_MFMA(BUF, SET) do {                                           \
    int lsw = SWZ(lane) << 4;                                            \
    __builtin_amdgcn_s_setprio(1);                                       \
    _Pragma("unroll")                                                    \
    for (int q = 0; q < 4; ++q) {                                        \
      short8 bf1 = *(const short8*)((char*)B1s + (BUF)*8192 + (((wc << 2) + q) << 10) + lsw); \
      short8 bf3 = *(const short8*)((char*)B3s + (BUF)*8192 + (((wc << 2) + q) << 10) + lsw); \
      _Pragma("unroll")                                                  \
      for (int mi = 0; mi < 4; ++mi) {                                   \
        acc1[mi][q] = __builtin_amdgcn_mfma_f32_16x16x32_bf16(af##SET[mi], bf1, acc1[mi][q], 0, 0, 0); \
        acc3[mi][q] = __builtin_amdgcn_mfma_f32_16x16x32_bf16(af##SET[mi], bf3, acc3[mi][q], 0, 0, 0); \
      }                                                                  \
    }                                                                    \
    __builtin_amdgcn_s_setprio(0);                                       \
  } while (0)

  // 32 K-tiles, depth-2, interleaved issue (r19)
  F1_ALOAD(E); F1_BLOAD(E);      // t0
  F1_ALOAD(O); F1_BLOAD(O);      // t1
  for (int it = 0; it < 15; ++it) {
    F1_BWRITE(E, 0); WAIT_LGKM0(); BARS();
    F1_BLOAD(E);
    F1_MFMA(0, E);
    F1_ALOAD(E);
    BARX();
    F1_BWRITE(O, 1); WAIT_LGKM0(); BARS();
    F1_BLOAD(O);
    F1_MFMA(1, O);
    F1_ALOAD(O);
    BARX();
  }
  F1_BWRITE(E, 0); WAIT_LGKM0(); BARS(); F1_MFMA(0, E); BARX();
  F1_BWRITE(O, 1); WAIT_LGKM0(); BARS(); F1_MFMA(1, O);

  // epilogue: silu(acc1)*acc3 -> Hb (aliased arena) -> octet-major hO
  __syncthreads();
  int lr = (lane >> 4) << 2, lc = lane & 15;
  #pragma unroll
  for (int mi = 0; mi < 4; ++mi) {
    #pragma unroll
    for (int j = 0; j < 4; ++j) {
      int m = ((wr << 2) + mi) * 16 + lr + j;       // local row 0..127
      #pragma unroll
      for (int q = 0; q < 4; ++q) {
        int c = (wc << 6) + (q << 4) + lc;          // local col 0..127
        float a = acc1[mi][q][j];
        float gt = a / (1.f + __expf(-a));
        Hb[((size_t)(c >> 3) * BM + m) * 8 + (c & 7)] = f2bfs(gt * acc3[mi][q][j]);
      }
    }
  }
  __syncthreads();
  // Hb holds cols in 16 col-octets? NOTE: arena is 32KB = 128 rows x 16
  // col-octets x 8 halfwords = 16384 shorts -> fits exactly.
  int co = tid >> 4, ml0 = (tid & 15) << 3;         // 16 col-octets x 16 row-groups
  size_t fo = (size_t)(n0 >> 3) + co;
  #pragma unroll
  for (int i = 0; i < 8; ++i) {
    int ml = ml0 + i;
    short8 vq = *(const short8*)(Hb + ((size_t)co * BM + ml) * 8);
    *(short8*)(hE + (fo * PAD_ + m0 + ml) * 8) = vq;
  }
}

// ---------------- ffn2: 128x128 tile, compact bf16 eo store (r22) ----------------
__global__ __launch_bounds__(256, 3) void ffn2_kernel(
    const unsigned short* __restrict__ hO, const float* __restrict__ W2,
    const int* __restrict__ counts, unsigned short* __restrict__ eoO) {
  // grid 1536 = 8 xcd x (8 eg x 8 ni x 3 mb), mb fastest
  int bid = blockIdx.x;
  int r = bid & 7, u = bid >> 3;
  int mb = u % 3; int v = u / 3;
  int ni = v % 8; int eg = v / 8;
  int e = eg * 8 + r;
  int n0 = ni * BN;
  int m0 = mb * BM;
  int Me = min(counts[e], PAD_);
  if (m0 >= Me) return;

  const unsigned short* AO = hO + (size_t)e * PAD_ * DFF_;
  const float* Bw = W2 + (size_t)e * DFF_ * D_ + n0;

  __shared__ short Bs[2 * BK * BN];    // 2 x 8KB

  int tid = threadIdx.x;
  int lane = tid & 63;
  int wv = tid >> 6, wr = wv >> 1, wc = wv & 1;

  // B staging: all 256 threads; thread: 4 k-rows x 4 cols.
  int col4 = tid & 31;
  int krow0 = (tid >> 5) << 2;
  const float* qB = Bw + (size_t)krow0 * D_ + col4 * 4;
  int kseg = krow0 >> 3, khalf8 = ((krow0 >> 2) & 1) << 3;
  int boffc[4];
  #pragma unroll
  for (int cc = 0; cc < 4; ++cc) {
    int c = col4 * 4 + cc;
    boffc[cc] = ((c >> 4) << 10) + (SWZ((kseg << 4) + (c & 15)) << 4) + khalf8;
  }

  const unsigned short* qa =
      AO + (((size_t)(lane >> 4)) * PAD_ + m0 + (wr << 6) + (lane & 15)) * 8;

  short8 afE[4], afO[4];
  f32x4 fBE[4], fBO[4];
  f32x4 acc[4][4] = {};

#define F2_ALOAD(SET) do {                                               \
    _Pragma("unroll")                                                    \
    for (int mi = 0; mi < 4; ++mi)                                       \
      af##SET[mi] = *(const short8*)(qa + mi * 128);                     \
    qa += (size_t)4 * PAD_ * 8;                                          \
  } while (0)

#define F2_BLOAD(SET) do {                                               \
    _Pragma("unroll")                                                    \
    for (int j = 0; j < 4; ++j)                                          \
      fB##SET[j] = *(const f32x4*)(qB + (size_t)j * D_);                 \
    qB += (size_t)BK * D_;                                               \
  } while (0)

#define F2_BWRITE(SET, BUF) do {                                         \
    _Pragma("unroll")                                                    \
    for (int cc = 0; cc < 4; ++cc) {                                     \
      s16x4 w;                                                           \
      _Pragma("unroll")                                                  \
      for (int j = 0; j < 4; ++j) w[j] = f2bfs(fB##SET[j][cc]);          \
      *(s16x4*)((char*)Bs + (BUF)*8192 + boffc[cc]) = w;                 \
    }                                                                    \
  } while (0)

#define F2_MFMA(BUF, SET) do {                                           \
    int lsw = SWZ(lane) << 4;                                            \
    __builtin_amdgcn_s_setprio(1);                                       \
    _Pragma("unroll")                                                    \
    for (int q = 0; q < 4; ++q) {                                        \
      short8 bfr = *(const short8*)((char*)Bs + (BUF)*8192 + (((wc << 2) + q) << 10) + lsw); \
      _Pragma("unroll")                                                  \
      for (int mi = 0; mi < 4; ++mi)                                     \
        acc[mi][q] = __builtin_amdgcn_mfma_f32_16x16x32_bf16(af##SET[mi], bfr, acc[mi][q], 0, 0, 0); \
    }                                                                    \
    __builtin_amdgcn_s_setprio(0);                                       \
  } while (0)

  // 44 K-tiles, depth-2, interleaved issue
  F2_ALOAD(E); F2_BLOAD(E);
  F2_ALOAD(O); F2_BLOAD(O);
  for (int it = 0; it < 21; ++it) {
    F2_BWRITE(E, 0); WAIT_LGKM0(); BARS();
    F2_BLOAD(E);
    F2_MFMA(0, E);
    F2_ALOAD(E);
    BARX();
    F2_BWRITE(O, 1); WAIT_LGKM0(); BARS();
    F2_BLOAD(O);
    F2_MFMA(1, O);
    F2_ALOAD(O);
    BARX();
  }
  F2_BWRITE(E, 0); WAIT_LGKM0(); BARS(); F2_MFMA(0, E); BARX();
  F2_BWRITE(O, 1); WAIT_LGKM0(); BARS(); F2_MFMA(1, O);

  // epilogue: coalesced bf16 store of raw acc to eoO[e][m][D]
  unsigned short* eoE = eoO + (size_t)e * PAD_ * D_;
  int lr = (lane >> 4) << 2, lc = lane & 15;
  #pragma unroll
  for (int mi = 0; mi < 4; ++mi) {
    #pragma unroll
    for (int j = 0; j < 4; ++j) {
      int m = m0 + ((wr << 2) + mi) * 16 + lr + j;
      if (m < Me) {
        unsigned short* op = eoE + (size_t)m * D_ + n0 + (wc << 6) + lc;
        #pragma unroll
        for (int q = 0; q < 4; ++q)
          op[q << 4] = (unsigned short)f2bfs(acc[mi][q][j]);
      }
    }
  }
}

// ---------------- combine: y[t] = w1*eo1 + w2*eo2 ----------------
__global__ __launch_bounds__(256) void combine_kernel(
    const unsigned short* __restrict__ eoO, const int* __restrict__ pairE,
    const int* __restrict__ pairM, const float* __restrict__ pairW,
    float* __restrict__ y) {
  int t = blockIdx.x * 4 + (threadIdx.x >> 6);
  int lane = threadIdx.x & 63;
  int e1 = pairE[2 * t], m1 = pairM[2 * t];
  int e2 = pairE[2 * t + 1], m2 = pairM[2 * t + 1];
  float w1 = pairW[2 * t], w2 = pairW[2 * t + 1];
  float out[16];
  #pragma unroll
  for (int i = 0; i < 16; ++i) out[i] = 0.f;
  if (m1 >= 0) {
    const unsigned short* rp = eoO + ((size_t)e1 * PAD_ + m1) * D_ + lane * 16;
    short8 a = *(const short8*)rp, b = *(const short8*)(rp + 8);
    #pragma unroll
    for (int i = 0; i < 8; ++i) {
      out[i]     += w1 * bf2f((unsigned short)a[i]);
      out[8 + i] += w1 * bf2f((unsigned short)b[i]);
    }
  }
  if (m2 >= 0) {
    const unsigned short* rp = eoO + ((size_t)e2 * PAD_ + m2) * D_ + lane * 16;
    short8 a = *(const short8*)rp, b = *(const short8*)(rp + 8);
    #pragma unroll
    for (int i = 0; i < 8; ++i) {
      out[i]     += w2 * bf2f((unsigned short)a[i]);
      out[8 + i] += w2 * bf2f((unsigned short)b[i]);
    }
  }
  int b = t >> 11, s = t & (S_ - 1);
  float* yp = y + (size_t)(s * B_ + b) * D_ + lane * 16;
  #pragma unroll
  for (int v = 0; v < 4; ++v) {
    float4 o4 = make_float4(out[v * 4], out[v * 4 + 1], out[v * 4 + 2], out[v * 4 + 3]);
    *(float4*)(yp + v * 4) = o4;
  }
}

extern "C" void kernel_launch(void* const* d_in, const int* in_sizes, int n_in,
                              void* d_out, int out_size, void* d_ws, size_t ws_size,
                              hipStream_t stream) {
  const float* x  = (const float*)d_in[0];
  const float* Wg = (const float*)d_in[1];
  const float* W1 = (const float*)d_in[2];
  const float* W3 = (const float*)d_in[3];
  const float* W2 = (const float*)d_in[4];
  float* y = (float*)d_out;
  float* laux = y + (size_t)S_ * B_ * D_;

  char* ws = (char*)d_ws;
  float* probs  = (float*)(ws + OFF_PROBS);
  int*   counts = (int*)  (ws + OFF_COUNTS);
  float* mesum  = (float*)(ws + OFF_MESUM);
  int*   pairE  = (int*)  (ws + OFF_PAIRE);
  int*   pairM  = (int*)  (ws + OFF_PAIRM);
  float* pairW  = (float*)(ws + OFF_PAIRW);
  unsigned short* xbufO = (unsigned short*)(ws + OFF_XBUF);  // also eoO
  unsigned short* hO    = (unsigned short*)(ws + OFF_H);

  hipMemsetAsync(counts, 0, 512, stream);

  gate_kernel<<<T_ / 8, 256, 0, stream>>>(x, Wg, probs, counts, pairE, pairM, pairW, xbufO);
  me_kernel<<<E_, 256, 0, stream>>>(probs, mesum);
  finalize_kernel<<<1, 64, 0, stream>>>(counts, mesum, laux);
  ffn1_kernel<<<8 * 8 * 11 * 3, 256, 0, stream>>>(xbufO, W1, W3, counts, hO);
  ffn2_kernel<<<8 * 8 * 8 * 3, 256, 0, stream>>>(hO, W2, counts, xbufO);  // eoO aliases xbufO
  combine_kernel<<<T_ / 4, 256, 0, stream>>>(xbufO, pairE, pairM, pairW, y);
}